// Round 3
// baseline (2064.120 us; speedup 1.0000x reference)
//
#include <hip/hip_runtime.h>

// GRU-D fused scan, v5: full-row lanes at the 256-VGPR occupancy tier.
// R7 diagnosis: v2/v3/v4 all spilled ~58 dwords/thread (VGPR_Count pinned at
// 84 = 6-waves/EU tier despite budget attrs; WRITE_SIZE 45.7MB = one-time
// scratch writeback). Spill RELOADS = 178KB/block/step from L2 ~= 3100cyc
// = the entire measured 3272cyc step. All prior h-state work was masked.
// Fix: NT=512 (8 waves = 2/EU -> 256-reg budget, amdgpu_waves_per_eu(2,2)).
// 6 dot waves: ONE full gate-row per lane (216 h2 weights: wih0 24pad +
// whh0 64 + wih1 64 + whh1 64) -> demand ~245 fits the 256 tier, and no
// K-split partial combine. Operand vector v_op = [hx24|h0 64|h1 64] h2 in
// LDS, read wave-uniform (same addr all lanes = conflict-free broadcast,
// 38 ds_read_b128/wave). Lanes write complete preacts to LDS (gx/gh split
// kept only for n-rows). Waves 6/7 = h0/h1 updaters (2 units/lane).
// 2 barriers/step, impute on wave 0 during update phase, as before.

#define BB 256
#define SS 1024
#define DD 32
#define HH 128
#define NT 512

typedef _Float16 f16;
typedef __attribute__((ext_vector_type(2))) _Float16 h2;

__device__ inline h2 as_h2(int x) { union { int i; h2 h; } u; u.i = x; return u.h; }

__device__ inline float dot2(h2 a, h2 b, float c) {
    return __builtin_amdgcn_fdot2(a, b, c, false);
}

__device__ inline float frcp(float x) { return __builtin_amdgcn_rcpf(x); }
__device__ inline float fast_sigm(float x) { return frcp(1.0f + __expf(-x)); }
__device__ inline float fast_tanh(float x) {
    x = fminf(15.0f, fmaxf(-15.0f, x));
    float e = __expf(-2.0f * x);
    return (1.0f - e) * frcp(1.0f + e);
}

struct ImpState { float xprev, tprev; bool hasprev; };

// Wave 0 only (all 64 lanes active in the ballot). Lane l<32 owns feature l.
__device__ inline void impute_store(int i, float xv, int l, ImpState& st,
                                    f16* hxs, const float* tb) {
    bool nanp = (l < 32) && (xv != xv);
    unsigned long long bal = __ballot(nanp);
    bool mask = bal != 0ull;
    if (l < 32) {
        float imp = mask ? st.xprev : xv;
        hxs[l] = (f16)imp;
        if (!mask) st.xprev = xv;
    }
    float tcur = tb[i];
    float tdel = (i == 0) ? 0.0f : (tcur - tb[i - 1]);
    float texp = st.hasprev ? (tcur - st.tprev) : tdel;
    if (l == 32) hxs[32] = (f16)(mask ? 1.0f : 0.0f);
    if (l == 33) hxs[33] = (f16)texp;
    if (!mask) { st.hasprev = true; st.tprev = tcur; }
}

__global__
__attribute__((amdgpu_flat_work_group_size(NT, NT), amdgpu_waves_per_eu(2, 2)))
void gru_fused(
    const float* __restrict__ t_in, const float* __restrict__ x_in,
    const float* __restrict__ Wih0, const float* __restrict__ Whh0,
    const float* __restrict__ bih0, const float* __restrict__ bhh0,
    const float* __restrict__ Wih1, const float* __restrict__ Whh1,
    const float* __restrict__ bih1, const float* __restrict__ bhh1,
    float* __restrict__ out, char* __restrict__ ws)
{
    // operand vector, dwords: hx [0,24), h0 [24,88), h1 [88,152)
    // f16 view:               hx [0,48), h0 [48,176), h1 [176,304)
    __shared__ __align__(16) int v_op[152];
    __shared__ float tb[SS];                     // timestamps (4 KB)
    __shared__ float g0[384], g1[384];           // preacts (gx+gh; gx for n-rows)
    __shared__ float g0n[128], g1n[128];         // gh part of n-rows

    const int tid = threadIdx.x;
    const int b = blockIdx.x;
    const bool isDot = tid < 384;    // waves 0-5: row r = tid
    const bool isU0  = (tid >= 384 && tid < 448);  // wave 6: h0 updater
    const bool isU1  = tid >= 448;                 // wave 7: h1 updater
    const int r = tid;               // gate row (dot lanes)
    const int lane = tid & 63;

    // ---- pack full row into registers (f32 -> f16x2): 216 h2 ----
    h2 w_a[24], w_c[64], w_d[64], w_e[64];
    if (isDot) {
        const float* p = Wih0 + r * 34;          // 34 floats = 17 h2, pad to 24
        #pragma unroll
        for (int k = 0; k < 24; k++) {
            f16 lo = (k < 17) ? (f16)p[2*k]   : (f16)0.0f;
            f16 hi = (k < 17) ? (f16)p[2*k+1] : (f16)0.0f;
            h2 v = {lo, hi}; w_a[k] = v;
        }
        p = Whh0 + r * HH;
        #pragma unroll
        for (int k = 0; k < 64; k++) { h2 v = {(f16)p[2*k], (f16)p[2*k+1]}; w_c[k] = v; }
        p = Wih1 + r * HH;
        #pragma unroll
        for (int k = 0; k < 64; k++) { h2 v = {(f16)p[2*k], (f16)p[2*k+1]}; w_d[k] = v; }
        p = Whh1 + r * HH;
        #pragma unroll
        for (int k = 0; k < 64; k++) { h2 v = {(f16)p[2*k], (f16)p[2*k+1]}; w_e[k] = v; }
    }

    // ---- updater setup: 2 units per lane ----
    float ubi[3][2], ubh[3][2], hr[2] = {0.0f, 0.0f};
    if (isU0 || isU1) {
        const float* bi = isU0 ? bih0 : bih1;
        const float* bh = isU0 ? bhh0 : bhh1;
        #pragma unroll
        for (int q = 0; q < 3; q++)
            #pragma unroll
            for (int u = 0; u < 2; u++) {
                ubi[q][u] = bi[lane + 64*u + 128*q];
                ubh[q][u] = bh[lane + 64*u + 128*q];
            }
    }

    // ---- prologue ----
    for (int i2 = tid; i2 < SS; i2 += NT) tb[i2] = t_in[i2];
    if (tid < 152) v_op[tid] = 0;

    const float* xrow = x_in + (size_t)b * SS * DD + tid;   // deref only tid<32
    ImpState st; st.xprev = 0.0f; st.tprev = 0.0f; st.hasprev = false;

    __syncthreads();
    if (tid < 64) {
        float xv0 = (tid < 32) ? xrow[0] : 0.0f;
        impute_store(0, xv0, tid, st, (f16*)v_op, tb);
    }
    __syncthreads();

    const int4* vb = (const int4*)v_op;
    f16* hf = (f16*)v_op;

    for (int i = 0; i <= SS; ++i) {
        const bool doImp = (i + 1 < SS);

        // prefetch next x row for imputation (consumed in update phase)
        float xv_n = 0.0f;
        if (tid < 32 && doImp) xv_n = xrow[(size_t)(i + 1) * DD];

        if (isDot) {
            // ---- full-row dots; operands broadcast wave-uniform from LDS ----
            float accA = 0.0f;
            #pragma unroll
            for (int c = 0; c < 6; ++c) {
                int4 v = vb[c];
                accA = dot2(as_h2(v.x), w_a[4*c+0], accA);
                accA = dot2(as_h2(v.y), w_a[4*c+1], accA);
                accA = dot2(as_h2(v.z), w_a[4*c+2], accA);
                accA = dot2(as_h2(v.w), w_a[4*c+3], accA);
            }
            float c0=0.f,c1=0.f,d0=0.f,d1=0.f,e0=0.f,e1=0.f;
            #pragma unroll
            for (int c = 0; c < 16; ++c) {
                int4 v = vb[6 + c];
                c0 = dot2(as_h2(v.x), w_c[4*c+0], c0);
                d0 = dot2(as_h2(v.x), w_d[4*c+0], d0);
                c1 = dot2(as_h2(v.y), w_c[4*c+1], c1);
                d1 = dot2(as_h2(v.y), w_d[4*c+1], d1);
                c0 = dot2(as_h2(v.z), w_c[4*c+2], c0);
                d0 = dot2(as_h2(v.z), w_d[4*c+2], d0);
                c1 = dot2(as_h2(v.w), w_c[4*c+3], c1);
                d1 = dot2(as_h2(v.w), w_d[4*c+3], d1);
            }
            #pragma unroll
            for (int c = 0; c < 16; ++c) {
                int4 v = vb[22 + c];
                e0 = dot2(as_h2(v.x), w_e[4*c+0], e0);
                e1 = dot2(as_h2(v.y), w_e[4*c+1], e1);
                e0 = dot2(as_h2(v.z), w_e[4*c+2], e0);
                e1 = dot2(as_h2(v.w), w_e[4*c+3], e1);
            }
            float accC = c0 + c1, accD = d0 + d1, accE = e0 + e1;
            if (r < 256) {            // wave-uniform branch (waves 0-3)
                g0[r] = accA + accC;
                g1[r] = accD + accE;
            } else {                  // n-rows: keep gx/gh separate (waves 4-5)
                g0[r] = accA; g0n[r - 256] = accC;
                g1[r] = accD; g1n[r - 256] = accE;
            }
        }
        __syncthreads();   // B1: preacts visible to updaters

        if (isU0 || isU1) {
            bool act = isU0 ? (i < SS) : (i > 0);
            if (act) {
                const float* G  = isU0 ? g0 : g1;
                const float* Gn = isU0 ? g0n : g1n;
                const int hbase = isU0 ? 48 : 176;
                #pragma unroll
                for (int u = 0; u < 2; ++u) {
                    int j = lane + 64*u;
                    float rg = fast_sigm(G[j]       + ubi[0][u] + ubh[0][u]);
                    float zg = fast_sigm(G[j + 128] + ubi[1][u] + ubh[1][u]);
                    float ng = fast_tanh(G[j + 256] + ubi[2][u]
                                         + rg * (Gn[j] + ubh[2][u]));
                    float h = (1.0f - zg) * ng + zg * hr[u];
                    hr[u] = h;
                    hf[hbase + j] = (f16)h;
                }
            }
        } else if (tid < 64 && doImp) {
            impute_store(i + 1, xv_n, tid, st, (f16*)v_op, tb);
        }
        __syncthreads();   // B2: new h / hx visible for next iteration
    }

    if (isU1) {
        out[(size_t)b * HH + lane]      = hr[0];
        out[(size_t)b * HH + lane + 64] = hr[1];
    }
}

extern "C" void kernel_launch(void* const* d_in, const int* in_sizes, int n_in,
                              void* d_out, int out_size, void* d_ws, size_t ws_size,
                              hipStream_t stream) {
    gru_fused<<<dim3(BB), dim3(NT), 0, stream>>>(
        (const float*)d_in[0], (const float*)d_in[1],
        (const float*)d_in[2], (const float*)d_in[3],
        (const float*)d_in[4], (const float*)d_in[5],
        (const float*)d_in[6], (const float*)d_in[7],
        (const float*)d_in[8], (const float*)d_in[9],
        (float*)d_out, (char*)d_ws);
}

// Round 4
// 1349.090 us; speedup vs baseline: 1.5300x; 1.5300x over previous
//
#include <hip/hip_runtime.h>

// GRU-D fused scan, v6: v3 + anti-rematerialization register pins.
// R8 diagnosis: the RA was never "capping" registers per se — LLVM
// REMATERIALIZES the packed weights (loads of loop-invariant __restrict__
// global + f32->f16 cvt are "free to recompute"), re-loading ~60-100
// dwords/thread from L2 EVERY step. Evidence: v5 allocated 128 VGPRs for a
// 216-dword demand yet spilled only 16 dwords (WRITE 8.2MB); v2/v3/v4 sat
// at 84 VGPRs regardless of occupancy attrs, step time == L2-reload floor.
// Fix: empty `asm volatile("" : "+v"(w))` on every packed h2 weight makes
// each an opaque asm-def -> cannot be remat'd from global; with
// waves_per_eu(3,3) budget = 168 regs, 105 weight dwords + ~45 temps fit
// resident. Structure identical to v3 (NT=768, LDS-broadcast h-state,
// uniform ds_read_b128, planar float2 partials, 2 barriers/step).

#define BB 256
#define SS 1024
#define DD 32
#define HH 128
#define NT 768

typedef _Float16 f16;
typedef __attribute__((ext_vector_type(2))) _Float16 h2;

__device__ inline h2 as_h2(int x) { union { int i; h2 h; } u; u.i = x; return u.h; }

__device__ inline float dot2(h2 a, h2 b, float c) {
    return __builtin_amdgcn_fdot2(a, b, c, false);
}

// Pin a packed weight into a VGPR as an opaque (non-rematerializable) value.
__device__ inline void pin(h2& v) { asm volatile("" : "+v"(v)); }

__device__ inline float frcp(float x) { return __builtin_amdgcn_rcpf(x); }
__device__ inline float fast_sigm(float x) { return frcp(1.0f + __expf(-x)); }
__device__ inline float fast_tanh(float x) {
    x = fminf(15.0f, fmaxf(-15.0f, x));
    float e = __expf(-2.0f * x);
    return (1.0f - e) * frcp(1.0f + e);
}

struct ImpState { float xprev, tprev; bool hasprev; };

// Wave 0 only (all 64 lanes active in the ballot). Lane l<32 owns feature l.
__device__ inline void impute_store(int i, float xv, int l, ImpState& st,
                                    f16* hxs, const float* tb) {
    bool nanp = (l < 32) && (xv != xv);
    unsigned long long bal = __ballot(nanp);
    bool mask = bal != 0ull;
    if (l < 32) {
        float imp = mask ? st.xprev : xv;
        hxs[l] = (f16)imp;
        if (!mask) st.xprev = xv;
    }
    float tcur = tb[i];
    float tdel = (i == 0) ? 0.0f : (tcur - tb[i - 1]);
    float texp = st.hasprev ? (tcur - st.tprev) : tdel;
    if (l == 32) hxs[32] = (f16)(mask ? 1.0f : 0.0f);
    if (l == 33) hxs[33] = (f16)texp;
    if (!mask) { st.hasprev = true; st.tprev = tcur; }
}

__global__
__attribute__((amdgpu_flat_work_group_size(NT, NT), amdgpu_waves_per_eu(3, 3)))
void gru_fused(
    const float* __restrict__ t_in, const float* __restrict__ x_in,
    const float* __restrict__ Wih0, const float* __restrict__ Whh0,
    const float* __restrict__ bih0, const float* __restrict__ bhh0,
    const float* __restrict__ Wih1, const float* __restrict__ Whh1,
    const float* __restrict__ bih1, const float* __restrict__ bhh1,
    float* __restrict__ out, char* __restrict__ ws)
{
    __shared__ float tb[SS];                  // timestamps (4 KB)
    __shared__ float2 pA[NT];                 // L0 partials (a,c) (6 KB)
    __shared__ float2 pB[NT];                 // L1 partials (d,e) (6 KB)
    __shared__ __align__(16) f16 h0s[HH];     // h0 state (256 B)
    __shared__ __align__(16) f16 h1s[HH];     // h1 state (256 B)
    __shared__ __align__(16) f16 hxs[48];     // imputed input, 34 used (96 B)

    const int tid = threadIdx.x;
    const int b = blockIdx.x;
    const int group = tid >= 384;       // K-half, wave-uniform (waves 0-5 / 6-11)
    const int row = tid - 384 * group;  // gate row 0..383

    // ---- pack this thread's half-rows into registers (f32 -> f16x2) ----
    h2 wih0[9], whh0[32], wih1[32], whh1[32];
    {
        const float* p = Wih0 + row * 34;
        const int lim = 8 + group;      // group0: 8 real pairs (+1 zero pad), group1: 9
        #pragma unroll
        for (int k = 0; k < 9; k++) {
            int e = 16 * group + 2 * k;
            f16 lo = (k < lim) ? (f16)p[e]     : (f16)0.0f;
            f16 hi = (k < lim) ? (f16)p[e + 1] : (f16)0.0f;
            h2 v = {lo, hi}; wih0[k] = v;
        }
        p = Whh0 + row * HH + 64 * group;
        #pragma unroll
        for (int k = 0; k < 32; k++) { h2 v = {(f16)p[2*k], (f16)p[2*k+1]}; whh0[k] = v; }
        p = Wih1 + row * HH + 64 * group;
        #pragma unroll
        for (int k = 0; k < 32; k++) { h2 v = {(f16)p[2*k], (f16)p[2*k+1]}; wih1[k] = v; }
        p = Whh1 + row * HH + 64 * group;
        #pragma unroll
        for (int k = 0; k < 32; k++) { h2 v = {(f16)p[2*k], (f16)p[2*k+1]}; whh1[k] = v; }
        // pin: block rematerialization of the packed registers
        #pragma unroll
        for (int k = 0; k < 9; k++)  pin(wih0[k]);
        #pragma unroll
        for (int k = 0; k < 32; k++) { pin(whh0[k]); pin(wih1[k]); pin(whh1[k]); }
    }

    // ---- updater setup: waves 8,9 -> h0 units; waves 10,11 -> h1 units ----
    const bool isU = (tid >= 512);
    const bool isU0 = (tid >= 512 && tid < 640);
    const int j = isU0 ? (tid - 512) : (tid - 640);   // hidden unit (updaters only)
    float ubi[3], ubh[3]; float hr = 0.0f;
    if (isU) {
        const float* bi = isU0 ? bih0 : bih1;
        const float* bh = isU0 ? bhh0 : bhh1;
        #pragma unroll
        for (int q = 0; q < 3; q++) { ubi[q] = bi[j + 128*q]; ubh[q] = bh[j + 128*q]; }
    }

    // ---- prologue: tb, zero state, impute(0) ----
    for (int i2 = tid; i2 < SS; i2 += NT) tb[i2] = t_in[i2];
    if (tid < 64)        ((int*)h0s)[tid]       = 0;
    else if (tid < 128)  ((int*)h1s)[tid - 64]  = 0;
    else if (tid < 152)  ((int*)hxs)[tid - 128] = 0;

    const float* xrow = x_in + (size_t)b * SS * DD + tid;   // deref only tid<32
    ImpState st; st.xprev = 0.0f; st.tprev = 0.0f; st.hasprev = false;

    __syncthreads();
    if (tid < 64) {
        float xv0 = (tid < 32) ? xrow[0] : 0.0f;
        impute_store(0, xv0, tid, st, hxs, tb);
    }
    __syncthreads();

    // wave-uniform LDS bases for this wave's K-half
    const int4* h0v  = (const int4*)(h0s + 64 * group);   // 8x int4 = 64 f16
    const int4* h1v  = (const int4*)(h1s + 64 * group);
    const int4* hxv4 = (const int4*)(hxs + 16 * group);   // 2x int4 = 16 f16
    const int*  hxep = (const int*)(hxs + 32);            // elements 32,33

    for (int i = 0; i <= SS; ++i) {
        const bool doL0 = (i < SS), doL1 = (i > 0), doImp = (i + 1 < SS);

        // prefetch next x row for imputation (overlaps with dot phase)
        float xv_n = 0.0f;
        if (tid < 32 && doImp) xv_n = xrow[(size_t)(i + 1) * DD];

        // ---- dots: h operands via uniform ds_read_b128 broadcast ----
        float aP = 0.0f;
        {
            int4 u0 = hxv4[0], u1 = hxv4[1];
            int he = *hxep;   // group0 pairs with zero weight wih0[8]
            aP = dot2(as_h2(u0.x), wih0[0], aP);
            aP = dot2(as_h2(u0.y), wih0[1], aP);
            aP = dot2(as_h2(u0.z), wih0[2], aP);
            aP = dot2(as_h2(u0.w), wih0[3], aP);
            aP = dot2(as_h2(u1.x), wih0[4], aP);
            aP = dot2(as_h2(u1.y), wih0[5], aP);
            aP = dot2(as_h2(u1.z), wih0[6], aP);
            aP = dot2(as_h2(u1.w), wih0[7], aP);
            aP = dot2(as_h2(he),   wih0[8], aP);
        }
        float cC[4] = {0,0,0,0}, dC[4] = {0,0,0,0}, eC[4] = {0,0,0,0};
        #pragma unroll
        for (int c = 0; c < 8; ++c) {
            int4 v = h0v[c];
            cC[0] = dot2(as_h2(v.x), whh0[4*c+0], cC[0]);
            dC[0] = dot2(as_h2(v.x), wih1[4*c+0], dC[0]);
            cC[1] = dot2(as_h2(v.y), whh0[4*c+1], cC[1]);
            dC[1] = dot2(as_h2(v.y), wih1[4*c+1], dC[1]);
            cC[2] = dot2(as_h2(v.z), whh0[4*c+2], cC[2]);
            dC[2] = dot2(as_h2(v.z), wih1[4*c+2], dC[2]);
            cC[3] = dot2(as_h2(v.w), whh0[4*c+3], cC[3]);
            dC[3] = dot2(as_h2(v.w), wih1[4*c+3], dC[3]);
        }
        #pragma unroll
        for (int c = 0; c < 8; ++c) {
            int4 v = h1v[c];
            eC[0] = dot2(as_h2(v.x), whh1[4*c+0], eC[0]);
            eC[1] = dot2(as_h2(v.y), whh1[4*c+1], eC[1]);
            eC[2] = dot2(as_h2(v.z), whh1[4*c+2], eC[2]);
            eC[3] = dot2(as_h2(v.w), whh1[4*c+3], eC[3]);
        }
        float cP = (cC[0] + cC[1]) + (cC[2] + cC[3]);
        float dP = (dC[0] + dC[1]) + (dC[2] + dC[3]);
        float eP = (eC[0] + eC[1]) + (eC[2] + eC[3]);
        pA[tid] = make_float2(aP, cP);
        pB[tid] = make_float2(dP, eP);
        __syncthreads();   // B1 (lgkm only)

        // ---- update phase ----
        if (isU) {
            bool act = isU0 ? doL0 : doL1;
            if (act) {
                const float2* P = isU0 ? pA : pB;
                float2 q0a = P[j],       q0b = P[384 + j];
                float2 q1a = P[j + 128], q1b = P[384 + j + 128];
                float2 q2a = P[j + 256], q2b = P[384 + j + 256];
                float rx = q0a.x + q0b.x, rh = q0a.y + q0b.y;
                float zx = q1a.x + q1b.x, zh = q1a.y + q1b.y;
                float nx = q2a.x + q2b.x, nh = q2a.y + q2b.y;
                float r = fast_sigm(ubi[0] + ubh[0] + rx + rh);
                float z = fast_sigm(ubi[1] + ubh[1] + zx + zh);
                float n = fast_tanh(ubi[2] + nx + r * (ubh[2] + nh));
                hr = (1.0f - z) * n + z * hr;
                f16* hp = isU0 ? h0s : h1s;
                hp[j] = (f16)hr;          // LDS write, drained at B2
            }
        } else if (tid < 64 && doImp) {
            impute_store(i + 1, xv_n, tid, st, hxs, tb);
        }
        __syncthreads();   // B2 (lgkm only) -> h/hx visible for next iter
    }

    if (tid >= 640) out[(size_t)b * HH + (tid - 640)] = hr;
}

extern "C" void kernel_launch(void* const* d_in, const int* in_sizes, int n_in,
                              void* d_out, int out_size, void* d_ws, size_t ws_size,
                              hipStream_t stream) {
    gru_fused<<<dim3(BB), dim3(NT), 0, stream>>>(
        (const float*)d_in[0], (const float*)d_in[1],
        (const float*)d_in[2], (const float*)d_in[3],
        (const float*)d_in[4], (const float*)d_in[5],
        (const float*)d_in[6], (const float*)d_in[7],
        (const float*)d_in[8], (const float*)d_in[9],
        (float*)d_out, (char*)d_ws);
}